// Round 25
// baseline (151.133 us; speedup 1.0000x reference)
//
#include <hip/hip_runtime.h>
#include <hip/hip_bf16.h>
#include <hip/hip_fp16.h>
#include <math.h>

typedef float f32x4 __attribute__((ext_vector_type(4)));
typedef short s16x8 __attribute__((ext_vector_type(8)));
typedef short s16x16 __attribute__((ext_vector_type(16)));

#define B_  4
#define D_  512
#define L_  8192
#define CH_ 512
#define M_  1024   // interleaved (h,g) rows

typedef const __attribute__((address_space(1))) void g_cvoid;
typedef __attribute__((address_space(3))) void lds_void;

__device__ __forceinline__ unsigned short f2bf(float f) {
    union { float f; unsigned u; } v; v.f = f;
    unsigned r = v.u + 0x7FFFu + ((v.u >> 16) & 1u);
    return (unsigned short)(r >> 16);
}

// ---------------------------------------------------------------------------
// Kernel 1: normalize h_w / g_w rows, interleave into Wn[1024][512] bf16.
// ---------------------------------------------------------------------------
__global__ __launch_bounds__(256)
void prep_kernel(const float* __restrict__ h_w, const float* __restrict__ g_w,
                 unsigned short* __restrict__ Wn) {
    __shared__ float red[4];
    const int ch = blockIdx.x, t = threadIdx.x;
    {
        float v0 = h_w[ch * 512 + t], v1 = h_w[ch * 512 + t + 256];
        float ss = v0 * v0 + v1 * v1;
        #pragma unroll
        for (int off = 32; off > 0; off >>= 1) ss += __shfl_down(ss, off, 64);
        if ((t & 63) == 0) red[t >> 6] = ss;
        __syncthreads();
        float tot = red[0] + red[1] + red[2] + red[3];
        float scale = 1.f / (sqrtf(tot) + 1e-4f * sqrtf(512.f));
        Wn[(size_t)(2 * ch) * 512 + t]       = f2bf(v0 * scale);
        Wn[(size_t)(2 * ch) * 512 + t + 256] = f2bf(v1 * scale);
    }
    __syncthreads();
    if (ch >= 2) {
        float v0 = g_w[(ch - 2) * 512 + t], v1 = g_w[(ch - 2) * 512 + t + 256];
        float ss = v0 * v0 + v1 * v1;
        #pragma unroll
        for (int off = 32; off > 0; off >>= 1) ss += __shfl_down(ss, off, 64);
        if ((t & 63) == 0) red[t >> 6] = ss;
        __syncthreads();
        float tot = red[0] + red[1] + red[2] + red[3];
        float scale = 1.f / (sqrtf(tot) + 1e-4f * sqrtf(512.f));
        Wn[(size_t)(2 * ch + 1) * 512 + t]       = f2bf(v0 * scale);
        Wn[(size_t)(2 * ch + 1) * 512 + t + 256] = f2bf(v1 * scale);
    } else {
        Wn[(size_t)(2 * ch + 1) * 512 + t]       = 0;
        Wn[(size_t)(2 * ch + 1) * 512 + t + 256] = 0;
    }
}

// ---------------------------------------------------------------------------
// Kernel 1b: f32-normalized h_w row 1 -> w1n_g[512] (r12's reduction order).
// ---------------------------------------------------------------------------
__global__ __launch_bounds__(512)
void w1n_kernel(const float* __restrict__ h_w, float* __restrict__ w1n_g) {
    __shared__ float red[8];
    const int t = threadIdx.x;
    const int sg = t >> 6;
    const int lane = t & 63;
    float v = h_w[512 + t];
    float ss = v * v;
    #pragma unroll
    for (int off = 32; off > 0; off >>= 1) ss += __shfl_down(ss, off, 64);
    if (lane == 0) red[sg] = ss;
    __syncthreads();
    float tot = ((red[0] + red[1]) + (red[2] + red[3]))
              + ((red[4] + red[5]) + (red[6] + red[7]));
    float sc = 1.f / (sqrtf(tot) + 1e-4f * sqrtf(512.f));
    w1n_g[t] = v * sc;
}

// ---------------------------------------------------------------------------
// Kernel 2: fused conv+transpose+ch1-partials (r24 register-conv, green).
// ---------------------------------------------------------------------------
__global__ __launch_bounds__(256)
void convT_kernel(const float* __restrict__ x, const float* __restrict__ cw,
                  const float* __restrict__ w1n_g,
                  unsigned short* __restrict__ CT, float* __restrict__ Pp) {
    __shared__ float cvf[64][65];           // [l][d] f32 conv values
    const int t = threadIdx.x;
    const int l0 = blockIdx.x * 64, d0 = blockIdx.y * 64, b = blockIdx.z;
    const int r = t >> 2, q = t & 3;
    const int d = d0 + r;
    float w0 = cw[d * 5 + 0], w1 = cw[d * 5 + 1], w2 = cw[d * 5 + 2],
          w3 = cw[d * 5 + 3], w4 = cw[d * 5 + 4];
    float ss = w0 * w0 + w1 * w1 + w2 * w2 + w3 * w3 + w4 * w4;
    float scale = 1.f / (sqrtf(ss) + 1e-4f * sqrtf(5.f));
    w0 *= scale; w1 *= scale; w2 *= scale; w3 *= scale; w4 *= scale;

    const float* xr = x + (size_t)(b * 512 + d) * L_;
    const int lb = l0 + 16 * q - 4;         // global l of xv[0] (4-aligned)
    float xv[24];
    #pragma unroll
    for (int v = 0; v < 6; ++v) {
        const int gl = lb + 4 * v;
        if (gl >= 0 && gl + 3 < L_) {
            float4 f = *(const float4*)&xr[gl];
            xv[4 * v + 0] = f.x; xv[4 * v + 1] = f.y;
            xv[4 * v + 2] = f.z; xv[4 * v + 3] = f.w;
        } else {
            #pragma unroll
            for (int e = 0; e < 4; ++e) {
                const int g2 = gl + e;
                xv[4 * v + e] = (g2 >= 0 && g2 < L_) ? xr[g2] : 0.f;
            }
        }
    }
    #pragma unroll
    for (int j = 0; j < 16; ++j) {
        float acc = w0 * xv[j + 2] + w1 * xv[j + 3] + w2 * xv[j + 4]
                  + w3 * xv[j + 5] + w4 * xv[j + 6];
        cvf[16 * q + j][r] = acc;
    }
    __syncthreads();
    {
        const int lr = t >> 2, seg = t & 3;
        unsigned short tmp[16];
        #pragma unroll
        for (int u = 0; u < 16; ++u)
            tmp[u] = f2bf(cvf[lr][seg * 16 + u]);
        *(s16x16*)&CT[(size_t)(b * 8192 + l0 + lr) * 512 + d0 + seg * 16] =
            *(const s16x16*)tmp;
    }
    if (t < 64) {
        float p = 0.f;
        for (int rr = 0; rr < 64; ++rr)
            p += w1n_g[d0 + rr] * cvf[t][rr];
        Pp[((size_t)blockIdx.y * B_ + b) * L_ + l0 + t] = p;
    }
}

// ---------------------------------------------------------------------------
// Kernel 3: bf16 MFMA GEMM.  R25: A-fragments loaded DIRECT global->VGPR
// (Wn is 1MB, L2-resident; quarter-wave access = 16 x 64B segments =
// well-coalesced) — As LDS tile deleted.  Per K-step: 4 gload_lds (B only,
// half the barrier payload) + 8 reg A-loads issued before the barrier
// (A latency hides under B's drain).  LDS 32->16KB (~4 blocks/CU).
// MFMA inputs bit-identical (same Wn rows/k).  r23 f16-packed epilogue.
// ---------------------------------------------------------------------------
__global__ __launch_bounds__(256)
void gemm_kernel(const unsigned short* __restrict__ Wn,
                 const unsigned short* __restrict__ CT,
                 unsigned* __restrict__ HG) {
    __shared__ unsigned short Bs[128 * 64];
    const int t = threadIdx.x;
    const int lane = t & 63, w = t >> 6;
    const int wgid = ((blockIdx.x & 7) << 8) | (blockIdx.x >> 3);
    const int mBase = (wgid & 7) * 128;
    const int nBase = (wgid >> 3) * 128;

    const int wrow = (w >> 1) * 64, wcol = (w & 1) * 64;

    const int srow_ = lane >> 3;                 // 0..7 within 8-row stripe
    const int schk  = (lane & 7) ^ srow_;        // inverse-swizzled global chunk

    f32x4 acc[4][4];
    #pragma unroll
    for (int fr = 0; fr < 4; ++fr)
        #pragma unroll
        for (int fc = 0; fc < 4; ++fc)
            acc[fr][fc] = (f32x4){0.f, 0.f, 0.f, 0.f};

    const unsigned short* gB = &CT[(size_t)(nBase + w * 32 + srow_) * 512 + schk * 8];

    const int g  = lane >> 4;
    // A direct-global fragment base: row = mBase+wrow+(lane&15), k = g*8
    const unsigned short* gAf = &Wn[(size_t)(mBase + wrow + (lane & 15)) * 512 + g * 8];
    const int c0 = ((0 + g) ^ (lane & 7)) * 8;    // B kh=0 swizzled chunk
    const int c1 = ((4 + g) ^ (lane & 7)) * 8;    // B kh=1

    #pragma unroll
    for (int ks = 0; ks < 8; ++ks) {
        const int k0 = ks * 64;
        #pragma unroll
        for (int i = 0; i < 4; ++i) {
            __builtin_amdgcn_global_load_lds(
                (g_cvoid*)(gB + (size_t)i * 8 * 512 + k0),
                (lds_void*)&Bs[(w * 32 + i * 8) * 64], 16, 0, 0);
        }
        s16x8 aF[2][4];
        #pragma unroll
        for (int kh = 0; kh < 2; ++kh)
            #pragma unroll
            for (int f = 0; f < 4; ++f)
                aF[kh][f] = *(const s16x8*)(gAf + (size_t)f * 16 * 512 + k0 + kh * 32);
        __syncthreads();
        #pragma unroll
        for (int kh = 0; kh < 2; ++kh) {
            const int cc = (kh == 0) ? c0 : c1;
            s16x8 bf[4];
            #pragma unroll
            for (int f = 0; f < 4; ++f)
                bf[f] = *(const s16x8*)&Bs[(wcol + f * 16 + (lane & 15)) * 64 + cc];
            #pragma unroll
            for (int fr = 0; fr < 4; ++fr)
                #pragma unroll
                for (int fc = 0; fc < 4; ++fc)
                    acc[fr][fc] = __builtin_amdgcn_mfma_f32_16x16x32_bf16(
                        aF[kh][fr], bf[fc], acc[fr][fc], 0, 0, 0);
        }
        __syncthreads();
    }

    #pragma unroll
    for (int fr = 0; fr < 4; ++fr)
    #pragma unroll
    for (int fc = 0; fc < 4; ++fc) {
        f32x4 a = acc[fr][fc];
        const int gR0 = mBase + wrow + fr * 16 + ((lane >> 4) * 4);
        const int n   = nBase + wcol + fc * 16 + (lane & 15);
        const int bb  = n >> 13, l = n & 8191;
        #pragma unroll
        for (int p = 0; p < 2; ++p) {
            float hv = a[2 * p], gv = a[2 * p + 1];
            const int ch = (gR0 >> 1) + p;
            if (ch == 0)      gv = -1000.f;
            else if (ch == 1) gv =  1000.f;
            float e  = __expf(-fabsf(gv));
            float l1 = __logf(1.f + e);                 // log1p(exp(-|g|))
            float la = fminf(-gv, 0.f) - l1;            // logsig(-g) <= 0
            float ls = fminf(gv, 0.f) - l1;             // logsig(g)
            float zb = ls + __logf(fmaxf(fabsf(hv), 1e-6f));
            float enc = (hv < 0.f) ? -la : la;          // sign(h) in sign bit
            unsigned short ula = __half_as_ushort(__float2half(enc));
            unsigned short uzb = __half_as_ushort(__float2half(zb));
            size_t off = ((size_t)bb * CH_ + ch) * L_ + l;
            HG[off] = ((unsigned)uzb << 16) | (unsigned)ula;
        }
    }
}

// ---------------------------------------------------------------------------
// Kernel 4: log-space scan from packed f16 (la_enc, zb) — r23 validated.
// ---------------------------------------------------------------------------
struct LV { float re, sg; };

__device__ __forceinline__ LV lcomb(LV a, LV b) {
    float m  = fmaxf(a.re, b.re);
    float ms = (m > -3.0e38f) ? m : 0.f;
    float s  = a.sg * __expf(a.re - ms) + b.sg * __expf(b.re - ms);
    LV r;
    r.re = ms + __logf(fabsf(s));
    r.sg = (s < 0.f) ? -1.f : 1.f;
    return r;
}

__global__ __launch_bounds__(512)
void logscan_kernel(const unsigned* __restrict__ HG,
                    const float* __restrict__ Pp,
                    float* __restrict__ Out) {
    __shared__ float wA[8];
    __shared__ float wRe[8], wSg[8];
    const int row = blockIdx.x;
    const int t = threadIdx.x;
    const int lane = t & 63, wid = t >> 6;
    const bool isCh1 = ((row & 511) == 1);
    const int bb = row >> 9;
    const unsigned* hp = HG + (size_t)row * L_;
    float* op = Out + (size_t)row * L_;

    float As[16], zz[16];
    unsigned sgb = 0;
    float run = 0.f;
    if (isCh1) {
        #pragma unroll
        for (int i = 0; i < 16; ++i) {
            const int l = t * 16 + i;
            float acc = Pp[((size_t)0 * B_ + bb) * L_ + l];
            #pragma unroll
            for (int gg = 1; gg < 8; ++gg)
                acc += Pp[((size_t)gg * B_ + bb) * L_ + l];
            if (acc < 0.f) sgb |= (1u << i);
            run -= 1000.f;                    // la = -1000 exact (logsig(1000)=0)
            As[i] = run;
            zz[i] = logf(fmaxf(fabsf(acc), 1e-6f));   // zb (software logf)
        }
    } else {
        #pragma unroll
        for (int i = 0; i < 4; ++i) {
            uint4 h4 = *(const uint4*)&hp[t * 16 + i * 4];
            #pragma unroll
            for (int j = 0; j < 4; ++j) {
                int k = i * 4 + j;
                unsigned w32 = (j == 0) ? h4.x : (j == 1) ? h4.y
                             : (j == 2) ? h4.z : h4.w;
                unsigned short ula = (unsigned short)(w32 & 0xFFFFu);
                unsigned short uzb = (unsigned short)(w32 >> 16);
                float enc = __half2float(__ushort_as_half(ula));
                float zbv = __half2float(__ushort_as_half(uzb));
                if (!(ula >> 15)) sgb |= (1u << k);   // sign bit 0 => h<0
                run -= fabsf(enc);                    // la = -|enc|
                As[k] = run;
                zz[k] = zbv;
            }
        }
    }
    float wsc = run;
    #pragma unroll
    for (int off = 1; off < 64; off <<= 1) {
        float u = __shfl_up(wsc, off, 64);
        if (lane >= off) wsc += u;
    }
    if (lane == 63) wA[wid] = wsc;
    __syncthreads();
    float pre = wsc - run;
    for (int j = 0; j < wid; ++j) pre += wA[j];
    #pragma unroll
    for (int i = 0; i < 16; ++i) As[i] += pre;

    // max-first per-thread reduction: z = zb - A*, independent exps
    float mstar = -INFINITY;
    #pragma unroll
    for (int k = 0; k < 16; ++k) {
        zz[k] -= As[k];
        mstar = fmaxf(mstar, zz[k]);
    }
    float ssum = 0.f;
    #pragma unroll
    for (int k = 0; k < 16; ++k)
        ssum += (((sgb >> k) & 1) ? -1.f : 1.f) * __expf(zz[k] - mstar);
    LV sc;
    sc.re = mstar + __logf(fabsf(ssum));
    sc.sg = (ssum < 0.f) ? -1.f : 1.f;

    #pragma unroll
    for (int off = 1; off < 64; off <<= 1) {
        float ure = __shfl_up(sc.re, off, 64);
        float usg = __shfl_up(sc.sg, off, 64);
        if (lane >= off) { LV u = { ure, usg }; sc = lcomb(u, sc); }
    }
    if (lane == 63) { wRe[wid] = sc.re; wSg[wid] = sc.sg; }
    __syncthreads();
    float pr = __shfl_up(sc.re, 1, 64);
    float ps = __shfl_up(sc.sg, 1, 64);
    LV lex = { -INFINITY, 1.f };
    if (lane != 0) { lex.re = pr; lex.sg = ps; }
    LV wpre = { -INFINITY, 1.f };
    for (int j = 0; j < wid; ++j) { LV u = { wRe[j], wSg[j] }; wpre = lcomb(wpre, u); }
    LV pref = lcomb(wpre, lex);

    // final: branchless running (m,s) update + output exp
    float m2 = pref.re;
    float s2 = pref.sg;
    #pragma unroll
    for (int i = 0; i < 4; ++i) {
        float4 o4;
        #pragma unroll
        for (int j = 0; j < 4; ++j) {
            int k = i * 4 + j;
            float sk = ((sgb >> k) & 1) ? -1.f : 1.f;
            float nm = fmaxf(m2, zz[k]);
            s2 = s2 * __expf(m2 - nm) + sk * __expf(zz[k] - nm);
            m2 = nm;
            float ov = s2 * __expf(As[k] + m2);
            if (j == 0) o4.x = ov; else if (j == 1) o4.y = ov;
            else if (j == 2) o4.z = ov; else o4.w = ov;
        }
        *(float4*)&op[t * 16 + i * 4] = o4;
    }
}

// ---------------------------------------------------------------------------
extern "C" void kernel_launch(void* const* d_in, const int* in_sizes, int n_in,
                              void* d_out, int out_size, void* d_ws, size_t ws_size,
                              hipStream_t stream) {
    const float* x      = (const float*)d_in[0];
    const float* conv_w = (const float*)d_in[1];
    const float* h_w    = (const float*)d_in[2];
    const float* g_w    = (const float*)d_in[3];
    float* out = (float*)d_out;
    char* ws = (char*)d_ws;

    // ws layout: CT bf16 32MB | Wn bf16 1MB | HG u32 32MB (in 64MB slot)
    // | w1n 16KB | Pp 1MB  (same offsets as r17-r24)
    unsigned short* CT  = (unsigned short*)ws;
    unsigned short* Wn  = (unsigned short*)(ws + (size_t)32 * 1024 * 1024);
    unsigned*       HG  = (unsigned*)(ws + (size_t)33 * 1024 * 1024);
    const size_t base97 = (size_t)97 * 1024 * 1024;
    float* w1n_g = (float*)(ws + base97);
    float* Pp    = (float*)(ws + base97 + 16 * 1024);

    prep_kernel<<<512, 256, 0, stream>>>(h_w, g_w, Wn);
    w1n_kernel<<<1, 512, 0, stream>>>(h_w, w1n_g);
    convT_kernel<<<dim3(128, 8, 4), 256, 0, stream>>>(x, conv_w, w1n_g, CT, Pp);
    gemm_kernel<<<2048, 256, 0, stream>>>(Wn, CT, HG);
    logscan_kernel<<<B_ * CH_, 512, 0, stream>>>(HG, Pp, out);
}

// Round 26
// 123.621 us; speedup vs baseline: 1.2226x; 1.2226x over previous
//
#include <hip/hip_runtime.h>
#include <hip/hip_bf16.h>
#include <hip/hip_fp16.h>
#include <math.h>

typedef float f32x4 __attribute__((ext_vector_type(4)));
typedef short s16x8 __attribute__((ext_vector_type(8)));
typedef short s16x16 __attribute__((ext_vector_type(16)));

#define B_  4
#define D_  512
#define L_  8192
#define CH_ 512
#define M_  1024   // interleaved (h,g) rows

typedef const __attribute__((address_space(1))) void g_cvoid;
typedef __attribute__((address_space(3))) void lds_void;

__device__ __forceinline__ unsigned short f2bf(float f) {
    union { float f; unsigned u; } v; v.f = f;
    unsigned r = v.u + 0x7FFFu + ((v.u >> 16) & 1u);
    return (unsigned short)(r >> 16);
}

// ---------------------------------------------------------------------------
// Kernel 1: normalize h_w / g_w rows, interleave into Wn[1024][512] bf16.
// ---------------------------------------------------------------------------
__global__ __launch_bounds__(256)
void prep_kernel(const float* __restrict__ h_w, const float* __restrict__ g_w,
                 unsigned short* __restrict__ Wn) {
    __shared__ float red[4];
    const int ch = blockIdx.x, t = threadIdx.x;
    {
        float v0 = h_w[ch * 512 + t], v1 = h_w[ch * 512 + t + 256];
        float ss = v0 * v0 + v1 * v1;
        #pragma unroll
        for (int off = 32; off > 0; off >>= 1) ss += __shfl_down(ss, off, 64);
        if ((t & 63) == 0) red[t >> 6] = ss;
        __syncthreads();
        float tot = red[0] + red[1] + red[2] + red[3];
        float scale = 1.f / (sqrtf(tot) + 1e-4f * sqrtf(512.f));
        Wn[(size_t)(2 * ch) * 512 + t]       = f2bf(v0 * scale);
        Wn[(size_t)(2 * ch) * 512 + t + 256] = f2bf(v1 * scale);
    }
    __syncthreads();
    if (ch >= 2) {
        float v0 = g_w[(ch - 2) * 512 + t], v1 = g_w[(ch - 2) * 512 + t + 256];
        float ss = v0 * v0 + v1 * v1;
        #pragma unroll
        for (int off = 32; off > 0; off >>= 1) ss += __shfl_down(ss, off, 64);
        if ((t & 63) == 0) red[t >> 6] = ss;
        __syncthreads();
        float tot = red[0] + red[1] + red[2] + red[3];
        float scale = 1.f / (sqrtf(tot) + 1e-4f * sqrtf(512.f));
        Wn[(size_t)(2 * ch + 1) * 512 + t]       = f2bf(v0 * scale);
        Wn[(size_t)(2 * ch + 1) * 512 + t + 256] = f2bf(v1 * scale);
    } else {
        Wn[(size_t)(2 * ch + 1) * 512 + t]       = 0;
        Wn[(size_t)(2 * ch + 1) * 512 + t + 256] = 0;
    }
}

// ---------------------------------------------------------------------------
// Kernel 1b: f32-normalized h_w row 1 -> w1n_g[512] (r12's reduction order).
// ---------------------------------------------------------------------------
__global__ __launch_bounds__(512)
void w1n_kernel(const float* __restrict__ h_w, float* __restrict__ w1n_g) {
    __shared__ float red[8];
    const int t = threadIdx.x;
    const int sg = t >> 6;
    const int lane = t & 63;
    float v = h_w[512 + t];
    float ss = v * v;
    #pragma unroll
    for (int off = 32; off > 0; off >>= 1) ss += __shfl_down(ss, off, 64);
    if (lane == 0) red[sg] = ss;
    __syncthreads();
    float tot = ((red[0] + red[1]) + (red[2] + red[3]))
              + ((red[4] + red[5]) + (red[6] + red[7]));
    float sc = 1.f / (sqrtf(tot) + 1e-4f * sqrtf(512.f));
    w1n_g[t] = v * sc;
}

// ---------------------------------------------------------------------------
// Kernel 2: fused conv+transpose+ch1-partials (r24 register-conv, green).
// ---------------------------------------------------------------------------
__global__ __launch_bounds__(256)
void convT_kernel(const float* __restrict__ x, const float* __restrict__ cw,
                  const float* __restrict__ w1n_g,
                  unsigned short* __restrict__ CT, float* __restrict__ Pp) {
    __shared__ float cvf[64][65];           // [l][d] f32 conv values
    const int t = threadIdx.x;
    const int l0 = blockIdx.x * 64, d0 = blockIdx.y * 64, b = blockIdx.z;
    const int r = t >> 2, q = t & 3;
    const int d = d0 + r;
    float w0 = cw[d * 5 + 0], w1 = cw[d * 5 + 1], w2 = cw[d * 5 + 2],
          w3 = cw[d * 5 + 3], w4 = cw[d * 5 + 4];
    float ss = w0 * w0 + w1 * w1 + w2 * w2 + w3 * w3 + w4 * w4;
    float scale = 1.f / (sqrtf(ss) + 1e-4f * sqrtf(5.f));
    w0 *= scale; w1 *= scale; w2 *= scale; w3 *= scale; w4 *= scale;

    const float* xr = x + (size_t)(b * 512 + d) * L_;
    const int lb = l0 + 16 * q - 4;         // global l of xv[0] (4-aligned)
    float xv[24];
    #pragma unroll
    for (int v = 0; v < 6; ++v) {
        const int gl = lb + 4 * v;
        if (gl >= 0 && gl + 3 < L_) {
            float4 f = *(const float4*)&xr[gl];
            xv[4 * v + 0] = f.x; xv[4 * v + 1] = f.y;
            xv[4 * v + 2] = f.z; xv[4 * v + 3] = f.w;
        } else {
            #pragma unroll
            for (int e = 0; e < 4; ++e) {
                const int g2 = gl + e;
                xv[4 * v + e] = (g2 >= 0 && g2 < L_) ? xr[g2] : 0.f;
            }
        }
    }
    #pragma unroll
    for (int j = 0; j < 16; ++j) {
        float acc = w0 * xv[j + 2] + w1 * xv[j + 3] + w2 * xv[j + 4]
                  + w3 * xv[j + 5] + w4 * xv[j + 6];
        cvf[16 * q + j][r] = acc;
    }
    __syncthreads();
    {
        const int lr = t >> 2, seg = t & 3;
        unsigned short tmp[16];
        #pragma unroll
        for (int u = 0; u < 16; ++u)
            tmp[u] = f2bf(cvf[lr][seg * 16 + u]);
        *(s16x16*)&CT[(size_t)(b * 8192 + l0 + lr) * 512 + d0 + seg * 16] =
            *(const s16x16*)tmp;
    }
    if (t < 64) {
        float p = 0.f;
        for (int rr = 0; rr < 64; ++rr)
            p += w1n_g[d0 + rr] * cvf[t][rr];
        Pp[((size_t)blockIdx.y * B_ + b) * L_ + l0 + t] = p;
    }
}

// ---------------------------------------------------------------------------
// Kernel 3: bf16 MFMA GEMM.  R26: r24 K-loop core (gload_lds for BOTH A and
// B — r25's A-direct regressed), tile widened 128x128 -> 128x256 with 8
// waves (512 thr).  Per-wave shape IDENTICAL to r24 (64x64 out, acc[4][4],
// same swizzle algebra; row bases stay multiples of 8/16).  Per block:
// 2x MFMA per barrier-pair, gload_lds per wave 8 -> 6.  LDS 48KB
// (3 blocks/CU x 8 waves).  MFMA inputs bit-identical.  f16 epilogue (r23).
// ---------------------------------------------------------------------------
__global__ __launch_bounds__(512)
void gemm_kernel(const unsigned short* __restrict__ Wn,
                 const unsigned short* __restrict__ CT,
                 unsigned* __restrict__ HG) {
    __shared__ unsigned short As[128 * 64];
    __shared__ unsigned short Bs[256 * 64];
    const int t = threadIdx.x;
    const int lane = t & 63, w = t >> 6;          // 8 waves
    const int wgid = ((blockIdx.x & 7) << 7) | (blockIdx.x >> 3);  // 1024 blocks
    const int mBase = (wgid & 7) * 128;
    const int nBase = (wgid >> 3) * 256;

    const int wrow = (w >> 2) * 64;               // 2 M-halves
    const int wcol = (w & 3) * 64;                // 4 N-quarters

    const int srow_ = lane >> 3;                  // 0..7 within 8-row stripe
    const int schk  = (lane & 7) ^ srow_;         // inverse-swizzled global chunk

    f32x4 acc[4][4];
    #pragma unroll
    for (int fr = 0; fr < 4; ++fr)
        #pragma unroll
        for (int fc = 0; fc < 4; ++fc)
            acc[fr][fc] = (f32x4){0.f, 0.f, 0.f, 0.f};

    // staging: wave w stages A rows [w*16, w*16+16) (2 instrs) and
    // B rows [w*32, w*32+32) (4 instrs)
    const unsigned short* gA = &Wn[(size_t)(mBase + w * 16 + srow_) * 512 + schk * 8];
    const unsigned short* gB = &CT[(size_t)(nBase + w * 32 + srow_) * 512 + schk * 8];

    const int g  = lane >> 4;
    const int c0 = ((0 + g) ^ (lane & 7)) * 8;    // kh=0 swizzled chunk
    const int c1 = ((4 + g) ^ (lane & 7)) * 8;    // kh=1

    #pragma unroll
    for (int ks = 0; ks < 8; ++ks) {
        const int k0 = ks * 64;
        #pragma unroll
        for (int i = 0; i < 2; ++i) {
            __builtin_amdgcn_global_load_lds(
                (g_cvoid*)(gA + (size_t)i * 8 * 512 + k0),
                (lds_void*)&As[(w * 16 + i * 8) * 64], 16, 0, 0);
        }
        #pragma unroll
        for (int i = 0; i < 4; ++i) {
            __builtin_amdgcn_global_load_lds(
                (g_cvoid*)(gB + (size_t)i * 8 * 512 + k0),
                (lds_void*)&Bs[(w * 32 + i * 8) * 64], 16, 0, 0);
        }
        __syncthreads();
        #pragma unroll
        for (int kh = 0; kh < 2; ++kh) {
            const int cc = (kh == 0) ? c0 : c1;
            s16x8 af[4], bf[4];
            #pragma unroll
            for (int f = 0; f < 4; ++f) {
                af[f] = *(const s16x8*)&As[(wrow + f * 16 + (lane & 15)) * 64 + cc];
                bf[f] = *(const s16x8*)&Bs[(wcol + f * 16 + (lane & 15)) * 64 + cc];
            }
            #pragma unroll
            for (int fr = 0; fr < 4; ++fr)
                #pragma unroll
                for (int fc = 0; fc < 4; ++fc)
                    acc[fr][fc] = __builtin_amdgcn_mfma_f32_16x16x32_bf16(
                        af[fr], bf[fc], acc[fr][fc], 0, 0, 0);
        }
        __syncthreads();
    }

    #pragma unroll
    for (int fr = 0; fr < 4; ++fr)
    #pragma unroll
    for (int fc = 0; fc < 4; ++fc) {
        f32x4 a = acc[fr][fc];
        const int gR0 = mBase + wrow + fr * 16 + ((lane >> 4) * 4);
        const int n   = nBase + wcol + fc * 16 + (lane & 15);
        const int bb  = n >> 13, l = n & 8191;
        #pragma unroll
        for (int p = 0; p < 2; ++p) {
            float hv = a[2 * p], gv = a[2 * p + 1];
            const int ch = (gR0 >> 1) + p;
            if (ch == 0)      gv = -1000.f;
            else if (ch == 1) gv =  1000.f;
            float e  = __expf(-fabsf(gv));
            float l1 = __logf(1.f + e);                 // log1p(exp(-|g|))
            float la = fminf(-gv, 0.f) - l1;            // logsig(-g) <= 0
            float ls = fminf(gv, 0.f) - l1;             // logsig(g)
            float zb = ls + __logf(fmaxf(fabsf(hv), 1e-6f));
            float enc = (hv < 0.f) ? -la : la;          // sign(h) in sign bit
            unsigned short ula = __half_as_ushort(__float2half(enc));
            unsigned short uzb = __half_as_ushort(__float2half(zb));
            size_t off = ((size_t)bb * CH_ + ch) * L_ + l;
            HG[off] = ((unsigned)uzb << 16) | (unsigned)ula;
        }
    }
}

// ---------------------------------------------------------------------------
// Kernel 4: log-space scan from packed f16 (la_enc, zb) — r23 validated.
// ---------------------------------------------------------------------------
struct LV { float re, sg; };

__device__ __forceinline__ LV lcomb(LV a, LV b) {
    float m  = fmaxf(a.re, b.re);
    float ms = (m > -3.0e38f) ? m : 0.f;
    float s  = a.sg * __expf(a.re - ms) + b.sg * __expf(b.re - ms);
    LV r;
    r.re = ms + __logf(fabsf(s));
    r.sg = (s < 0.f) ? -1.f : 1.f;
    return r;
}

__global__ __launch_bounds__(512)
void logscan_kernel(const unsigned* __restrict__ HG,
                    const float* __restrict__ Pp,
                    float* __restrict__ Out) {
    __shared__ float wA[8];
    __shared__ float wRe[8], wSg[8];
    const int row = blockIdx.x;
    const int t = threadIdx.x;
    const int lane = t & 63, wid = t >> 6;
    const bool isCh1 = ((row & 511) == 1);
    const int bb = row >> 9;
    const unsigned* hp = HG + (size_t)row * L_;
    float* op = Out + (size_t)row * L_;

    float As[16], zz[16];
    unsigned sgb = 0;
    float run = 0.f;
    if (isCh1) {
        #pragma unroll
        for (int i = 0; i < 16; ++i) {
            const int l = t * 16 + i;
            float acc = Pp[((size_t)0 * B_ + bb) * L_ + l];
            #pragma unroll
            for (int gg = 1; gg < 8; ++gg)
                acc += Pp[((size_t)gg * B_ + bb) * L_ + l];
            if (acc < 0.f) sgb |= (1u << i);
            run -= 1000.f;                    // la = -1000 exact (logsig(1000)=0)
            As[i] = run;
            zz[i] = logf(fmaxf(fabsf(acc), 1e-6f));   // zb (software logf)
        }
    } else {
        #pragma unroll
        for (int i = 0; i < 4; ++i) {
            uint4 h4 = *(const uint4*)&hp[t * 16 + i * 4];
            #pragma unroll
            for (int j = 0; j < 4; ++j) {
                int k = i * 4 + j;
                unsigned w32 = (j == 0) ? h4.x : (j == 1) ? h4.y
                             : (j == 2) ? h4.z : h4.w;
                unsigned short ula = (unsigned short)(w32 & 0xFFFFu);
                unsigned short uzb = (unsigned short)(w32 >> 16);
                float enc = __half2float(__ushort_as_half(ula));
                float zbv = __half2float(__ushort_as_half(uzb));
                if (!(ula >> 15)) sgb |= (1u << k);   // sign bit 0 => h<0
                run -= fabsf(enc);                    // la = -|enc|
                As[k] = run;
                zz[k] = zbv;
            }
        }
    }
    float wsc = run;
    #pragma unroll
    for (int off = 1; off < 64; off <<= 1) {
        float u = __shfl_up(wsc, off, 64);
        if (lane >= off) wsc += u;
    }
    if (lane == 63) wA[wid] = wsc;
    __syncthreads();
    float pre = wsc - run;
    for (int j = 0; j < wid; ++j) pre += wA[j];
    #pragma unroll
    for (int i = 0; i < 16; ++i) As[i] += pre;

    // max-first per-thread reduction: z = zb - A*, independent exps
    float mstar = -INFINITY;
    #pragma unroll
    for (int k = 0; k < 16; ++k) {
        zz[k] -= As[k];
        mstar = fmaxf(mstar, zz[k]);
    }
    float ssum = 0.f;
    #pragma unroll
    for (int k = 0; k < 16; ++k)
        ssum += (((sgb >> k) & 1) ? -1.f : 1.f) * __expf(zz[k] - mstar);
    LV sc;
    sc.re = mstar + __logf(fabsf(ssum));
    sc.sg = (ssum < 0.f) ? -1.f : 1.f;

    #pragma unroll
    for (int off = 1; off < 64; off <<= 1) {
        float ure = __shfl_up(sc.re, off, 64);
        float usg = __shfl_up(sc.sg, off, 64);
        if (lane >= off) { LV u = { ure, usg }; sc = lcomb(u, sc); }
    }
    if (lane == 63) { wRe[wid] = sc.re; wSg[wid] = sc.sg; }
    __syncthreads();
    float pr = __shfl_up(sc.re, 1, 64);
    float ps = __shfl_up(sc.sg, 1, 64);
    LV lex = { -INFINITY, 1.f };
    if (lane != 0) { lex.re = pr; lex.sg = ps; }
    LV wpre = { -INFINITY, 1.f };
    for (int j = 0; j < wid; ++j) { LV u = { wRe[j], wSg[j] }; wpre = lcomb(wpre, u); }
    LV pref = lcomb(wpre, lex);

    // final: branchless running (m,s) update + output exp
    float m2 = pref.re;
    float s2 = pref.sg;
    #pragma unroll
    for (int i = 0; i < 4; ++i) {
        float4 o4;
        #pragma unroll
        for (int j = 0; j < 4; ++j) {
            int k = i * 4 + j;
            float sk = ((sgb >> k) & 1) ? -1.f : 1.f;
            float nm = fmaxf(m2, zz[k]);
            s2 = s2 * __expf(m2 - nm) + sk * __expf(zz[k] - nm);
            m2 = nm;
            float ov = s2 * __expf(As[k] + m2);
            if (j == 0) o4.x = ov; else if (j == 1) o4.y = ov;
            else if (j == 2) o4.z = ov; else o4.w = ov;
        }
        *(float4*)&op[t * 16 + i * 4] = o4;
    }
}

// ---------------------------------------------------------------------------
extern "C" void kernel_launch(void* const* d_in, const int* in_sizes, int n_in,
                              void* d_out, int out_size, void* d_ws, size_t ws_size,
                              hipStream_t stream) {
    const float* x      = (const float*)d_in[0];
    const float* conv_w = (const float*)d_in[1];
    const float* h_w    = (const float*)d_in[2];
    const float* g_w    = (const float*)d_in[3];
    float* out = (float*)d_out;
    char* ws = (char*)d_ws;

    // ws layout: CT bf16 32MB | Wn bf16 1MB | HG u32 32MB (in 64MB slot)
    // | w1n 16KB | Pp 1MB  (same offsets as r17-r25)
    unsigned short* CT  = (unsigned short*)ws;
    unsigned short* Wn  = (unsigned short*)(ws + (size_t)32 * 1024 * 1024);
    unsigned*       HG  = (unsigned*)(ws + (size_t)33 * 1024 * 1024);
    const size_t base97 = (size_t)97 * 1024 * 1024;
    float* w1n_g = (float*)(ws + base97);
    float* Pp    = (float*)(ws + base97 + 16 * 1024);

    prep_kernel<<<512, 256, 0, stream>>>(h_w, g_w, Wn);
    w1n_kernel<<<1, 512, 0, stream>>>(h_w, w1n_g);
    convT_kernel<<<dim3(128, 8, 4), 256, 0, stream>>>(x, conv_w, w1n_g, CT, Pp);
    gemm_kernel<<<1024, 512, 0, stream>>>(Wn, CT, HG);
    logscan_kernel<<<B_ * CH_, 512, 0, stream>>>(HG, Pp, out);
}